// Round 9
// baseline (770.142 us; speedup 1.0000x reference)
//
#include <hip/hip_runtime.h>
#include <hip/hip_bf16.h>
#include <stdint.h>

#define SQ 2048
#define DK 64
#define NB 32
#define TQ 16
#define EW 2064            // bf16 elems per LDS score row
#define SCL 0.18033688011112042f   // log2(e)/8

typedef __attribute__((ext_vector_type(8))) short short8;
typedef __attribute__((ext_vector_type(4))) float f32x4;
typedef __attribute__((ext_vector_type(4))) unsigned u32x4;
typedef __attribute__((ext_vector_type(2))) unsigned u32x2;

// ---- bf16 helpers (RNE) ----
__device__ __forceinline__ unsigned f2bf_u(float x) {
    unsigned u = __builtin_bit_cast(unsigned, x);
    u += 0x7fffu + ((u >> 16) & 1u);
    return u >> 16;
}
__device__ __forceinline__ float bf2f(unsigned h) {
    return __builtin_bit_cast(float, h << 16);
}
__device__ __forceinline__ float bf2f_hi(unsigned u) {
    return __builtin_bit_cast(float, u & 0xffff0000u);
}
__device__ __forceinline__ void split8(const float* p, short8& h, short8& l) {
    f32x4 a = *(const f32x4*)p;
    f32x4 b = *(const f32x4*)(p + 4);
    #pragma unroll
    for (int j = 0; j < 4; ++j) {
        unsigned ua = f2bf_u(a[j]);
        h[j] = (short)ua; l[j] = (short)f2bf_u(a[j] - bf2f(ua));
        unsigned ub = f2bf_u(b[j]);
        h[j + 4] = (short)ub; l[j + 4] = (short)f2bf_u(b[j] - bf2f(ub));
    }
}

// ============ prep: K -> bf16 hi/lo planes; V -> transposed bf16 plane ============
__global__ __launch_bounds__(256) void prep_kernel(
    const float* __restrict__ K, const float* __restrict__ V,
    unsigned short* __restrict__ Khi, unsigned short* __restrict__ Klo,
    unsigned short* __restrict__ Vt)
{
    __shared__ float vtile[64][65];
    const int t  = threadIdx.x;
    const int b  = blockIdx.x >> 5;
    const int s0 = (blockIdx.x & 31) << 6;
    const size_t base = ((size_t)b * SQ + s0) * DK + (size_t)t * 16;

    {
        short8 h0, l0, h1, l1;
        split8(K + base,     h0, l0);
        split8(K + base + 8, h1, l1);
        *(short8*)(Khi + base)     = h0;
        *(short8*)(Khi + base + 8) = h1;
        *(short8*)(Klo + base)     = l0;
        *(short8*)(Klo + base + 8) = l1;
    }
    {
        const int sr = t >> 2, dc = (t & 3) << 4;
        #pragma unroll
        for (int u = 0; u < 16; u += 4) {
            f32x4 v = *(const f32x4*)(V + base + u);
            vtile[sr][dc + u + 0] = v[0];
            vtile[sr][dc + u + 1] = v[1];
            vtile[sr][dc + u + 2] = v[2];
            vtile[sr][dc + u + 3] = v[3];
        }
    }
    __syncthreads();
    #pragma unroll
    for (int rep = 0; rep < 16; ++rep) {
        const int idx = rep * 256 + t;
        const int d = idx >> 6, s = idx & 63;
        Vt[((size_t)b * DK + d) * SQ + s0 + s] = (unsigned short)f2bf_u(vtile[s][d]);
    }
}

// ============ K2: scores -> exp -> rowsum -> mask+normalize -> attn f32 ============
__global__ __launch_bounds__(512, 4) void qk_kernel(
    const float* __restrict__ Q, const unsigned short* __restrict__ Khi,
    const unsigned short* __restrict__ Klo, const unsigned* __restrict__ Mk,
    float* __restrict__ Aout)
{
    __shared__ __align__(16) unsigned short e_lds[TQ][EW];  // unmasked e, bf16
    __shared__ float rsum[8][TQ];
    __shared__ float i2s[TQ];

    const int tid  = threadIdx.x;
    const int lane = tid & 63;
    const int wv   = tid >> 6;
    const int m16  = lane & 15;
    const int kq   = lane >> 4;
    const int koff = kq * 8;

    // XCD batch-affinity swizzle: XCD x owns batches 4x..4x+3
    const int bx  = blockIdx.x;
    const int xcd = bx & 7;
    const int j   = bx >> 3;
    const int b   = xcd * 4 + (j >> 7);
    const int q0  = (j & 127) * TQ;

    // Q fragments (B-operand), split bf16
    short8 qh[2], ql[2];
    {
        const float* qrow = Q + ((size_t)b * SQ + q0 + m16) * DK;
        split8(qrow + koff,      qh[0], ql[0]);
        split8(qrow + 32 + koff, qh[1], ql[1]);
    }

    // ---- Phase A: e = exp(QK^T/8) -> bf16 LDS (unmasked); rowsum in-register ----
    float rs = 0.f;
    {
        const size_t krow = ((size_t)b * SQ + wv * 256 + m16) * DK;
        const unsigned short* khp = Khi + krow;
        const unsigned short* klp = Klo + krow;
        const int xw = (m16 & 7) << 3;
        for (int t = 0; t < 16; ++t) {
            const int off = t * 16 * DK;
            short8 kh0 = *(const short8*)(khp + off + koff);
            short8 kh1 = *(const short8*)(khp + off + 32 + koff);
            short8 kl0 = *(const short8*)(klp + off + koff);
            short8 kl1 = *(const short8*)(klp + off + 32 + koff);
            f32x4 a0 = {0.f, 0.f, 0.f, 0.f};
            f32x4 a1 = {0.f, 0.f, 0.f, 0.f};
            a0 = __builtin_amdgcn_mfma_f32_16x16x32_bf16(kh0, qh[0], a0, 0, 0, 0);
            a1 = __builtin_amdgcn_mfma_f32_16x16x32_bf16(kh1, qh[1], a1, 0, 0, 0);
            a0 = __builtin_amdgcn_mfma_f32_16x16x32_bf16(kh0, ql[0], a0, 0, 0, 0);
            a1 = __builtin_amdgcn_mfma_f32_16x16x32_bf16(kh1, ql[1], a1, 0, 0, 0);
            a0 = __builtin_amdgcn_mfma_f32_16x16x32_bf16(kl0, qh[0], a0, 0, 0, 0);
            a1 = __builtin_amdgcn_mfma_f32_16x16x32_bf16(kl1, qh[1], a1, 0, 0, 0);
            const float e0 = __builtin_amdgcn_exp2f((a0[0] + a1[0]) * SCL);
            const float e1 = __builtin_amdgcn_exp2f((a0[1] + a1[1]) * SCL);
            const float e2 = __builtin_amdgcn_exp2f((a0[2] + a1[2]) * SCL);
            const float e3 = __builtin_amdgcn_exp2f((a0[3] + a1[3]) * SCL);
            rs += (e0 + e1) + (e2 + e3);
            u32x2 pk;
            pk[0] = f2bf_u(e0) | (f2bf_u(e1) << 16);
            pk[1] = f2bf_u(e2) | (f2bf_u(e3) << 16);
            *(u32x2*)&e_lds[m16][(wv * 256 + t * 16 + kq * 4) ^ xw] = pk;
        }
    }
    rs += __shfl_xor(rs, 16);
    rs += __shfl_xor(rs, 32);
    if (lane < 16) rsum[wv][lane] = rs;
    __syncthreads();
    if (tid < 16) {
        float s = 0.f;
        #pragma unroll
        for (int w = 0; w < 8; ++w) s += rsum[w][tid];
        i2s[tid] = 2.0f / s;       // includes dropout keep-scale
    }
    __syncthreads();

    // ---- dump: mask (NT) + normalize + attn f32 store (NT); no barriers ----
    {
        const int cr = tid >> 5;
        const int cc = (tid & 31) * 8;
        const int xc = (cr & 7) << 3;
        const float i2 = i2s[cr];
        const size_t crow = ((size_t)b * SQ + q0 + cr) * SQ + cc;
        #pragma unroll
        for (int s = 0; s < 8; ++s) {
            const u32x4 ma = __builtin_nontemporal_load((const u32x4*)(Mk + crow + s * 256));
            const u32x4 mb = __builtin_nontemporal_load((const u32x4*)(Mk + crow + s * 256 + 4));
            const u32x4 ev = *(const u32x4*)&e_lds[cr][(s * 256 + cc) ^ xc];
            f32x4 o0, o1;
            o0[0] = ma[0] ? bf2f(ev[0] & 0xffffu) * i2 : 0.f;
            o0[1] = ma[1] ? bf2f_hi(ev[0]) * i2 : 0.f;
            o0[2] = ma[2] ? bf2f(ev[1] & 0xffffu) * i2 : 0.f;
            o0[3] = ma[3] ? bf2f_hi(ev[1]) * i2 : 0.f;
            o1[0] = mb[0] ? bf2f(ev[2] & 0xffffu) * i2 : 0.f;
            o1[1] = mb[1] ? bf2f_hi(ev[2]) * i2 : 0.f;
            o1[2] = mb[2] ? bf2f(ev[3] & 0xffffu) * i2 : 0.f;
            o1[3] = mb[3] ? bf2f_hi(ev[3]) * i2 : 0.f;
            __builtin_nontemporal_store(o0, (f32x4*)(Aout + crow + s * 256));
            __builtin_nontemporal_store(o1, (f32x4*)(Aout + crow + s * 256 + 4));
        }
    }
}

// ============ K3: y = attn (f32, final) x V  — no LDS, no barriers ============
__global__ __launch_bounds__(256, 8) void pv_kernel(
    const float* __restrict__ Attn, const unsigned short* __restrict__ Vt,
    float* __restrict__ Yout)
{
    const int tid  = threadIdx.x;
    const int lane = tid & 63;
    const int g    = tid >> 6;          // d-group 0..3 (one wave each)
    const int m16  = lane & 15;
    const int kq   = lane >> 4;
    const int koff = kq * 8;

    const int bx  = blockIdx.x;
    const int xcd = bx & 7;
    const int j   = bx >> 3;
    const int b   = xcd * 4 + (j >> 7);
    const int q0  = (j & 127) * TQ;

    const float*          arow = Attn + ((size_t)b * SQ + q0 + m16) * SQ;
    const unsigned short* vrow = Vt + ((size_t)b * DK + g * 16 + m16) * SQ;

    f32x4 accA = {0.f, 0.f, 0.f, 0.f};
    f32x4 accB = {0.f, 0.f, 0.f, 0.f};
    #pragma unroll 8
    for (int ch = 0; ch < 64; ch += 2) {
        {
            const int k0 = ch * 32;
            f32x4 p0 = *(const f32x4*)(arow + k0 + koff);
            f32x4 p1 = *(const f32x4*)(arow + k0 + koff + 4);
            short8 af;
            af[0] = (short)f2bf_u(p0[0]); af[1] = (short)f2bf_u(p0[1]);
            af[2] = (short)f2bf_u(p0[2]); af[3] = (short)f2bf_u(p0[3]);
            af[4] = (short)f2bf_u(p1[0]); af[5] = (short)f2bf_u(p1[1]);
            af[6] = (short)f2bf_u(p1[2]); af[7] = (short)f2bf_u(p1[3]);
            short8 vf = *(const short8*)(vrow + k0 + koff);
            accA = __builtin_amdgcn_mfma_f32_16x16x32_bf16(af, vf, accA, 0, 0, 0);
        }
        {
            const int k0 = (ch + 1) * 32;
            f32x4 p0 = *(const f32x4*)(arow + k0 + koff);
            f32x4 p1 = *(const f32x4*)(arow + k0 + koff + 4);
            short8 af;
            af[0] = (short)f2bf_u(p0[0]); af[1] = (short)f2bf_u(p0[1]);
            af[2] = (short)f2bf_u(p0[2]); af[3] = (short)f2bf_u(p0[3]);
            af[4] = (short)f2bf_u(p1[0]); af[5] = (short)f2bf_u(p1[1]);
            af[6] = (short)f2bf_u(p1[2]); af[7] = (short)f2bf_u(p1[3]);
            short8 vf = *(const short8*)(vrow + k0 + koff);
            accB = __builtin_amdgcn_mfma_f32_16x16x32_bf16(af, vf, accB, 0, 0, 0);
        }
    }
    // D layout: lane(m16,kq) reg r -> y[q0 + kq*4 + r][g*16 + m16]
    #pragma unroll
    for (int r = 0; r < 4; ++r) {
        const float yv = accA[r] + accB[r];
        __builtin_nontemporal_store(yv,
            Yout + ((size_t)b * SQ + q0 + kq * 4 + r) * DK + g * 16 + m16);
    }
}

extern "C" void kernel_launch(void* const* d_in, const int* in_sizes, int n_in,
                              void* d_out, int out_size, void* d_ws, size_t ws_size,
                              hipStream_t stream) {
    const float*    Q  = (const float*)d_in[0];
    const float*    K  = (const float*)d_in[1];
    const float*    V  = (const float*)d_in[2];
    const unsigned* Mk = (const unsigned*)d_in[3];
    float* Yout = (float*)d_out;
    float* Aout = (float*)d_out + (size_t)NB * SQ * DK;

    const size_t NEL = (size_t)NB * SQ * DK;
    unsigned short* Khi = (unsigned short*)d_ws;
    unsigned short* Klo = Khi + NEL;
    unsigned short* Vt  = Klo + NEL;

    prep_kernel<<<dim3(NB * (SQ / 64)), dim3(256), 0, stream>>>(K, V, Khi, Klo, Vt);
    qk_kernel<<<dim3(NB * (SQ / TQ)), dim3(512), 0, stream>>>(Q, Khi, Klo, Mk, Aout);
    pv_kernel<<<dim3(NB * (SQ / TQ)), dim3(256), 0, stream>>>(Aout, Vt, Yout);
}

// Round 10
// 470.393 us; speedup vs baseline: 1.6372x; 1.6372x over previous
//
#include <hip/hip_runtime.h>
#include <hip/hip_bf16.h>
#include <stdint.h>

#define SQ 2048
#define DK 64
#define NB 32
#define TQ 32              // q rows per block
#define EW 2064            // bf16 elems per LDS score row (pad)
#define SCL 0.18033688011112042f   // log2(e)/8

typedef __attribute__((ext_vector_type(8))) short short8;
typedef __attribute__((ext_vector_type(4))) float f32x4;
typedef __attribute__((ext_vector_type(4))) unsigned u32x4;
typedef __attribute__((ext_vector_type(2))) unsigned u32x2;

// ---- bf16 helpers ----
__device__ __forceinline__ unsigned f2bf_u(float x) {
    unsigned u = __builtin_bit_cast(unsigned, x);
    u += 0x7fffu + ((u >> 16) & 1u);
    return u >> 16;
}
__device__ __forceinline__ float bf2f(unsigned h) {
    return __builtin_bit_cast(float, h << 16);
}
__device__ __forceinline__ float bf2f_hi(unsigned u) {
    return __builtin_bit_cast(float, u & 0xffff0000u);
}
__device__ __forceinline__ unsigned cvtpk_bf16(float lo, float hi) {
    unsigned r;
    asm("v_cvt_pk_bf16_f32 %0, %1, %2" : "=v"(r) : "v"(lo), "v"(hi));
    return r;   // low16 = bf16(lo), high16 = bf16(hi)
}
__device__ __forceinline__ void split8(const float* p, short8& h, short8& l) {
    f32x4 a = *(const f32x4*)p;
    f32x4 b = *(const f32x4*)(p + 4);
    #pragma unroll
    for (int j = 0; j < 4; ++j) {
        unsigned ua = f2bf_u(a[j]);
        h[j] = (short)ua; l[j] = (short)f2bf_u(a[j] - bf2f(ua));
        unsigned ub = f2bf_u(b[j]);
        h[j + 4] = (short)ub; l[j + 4] = (short)f2bf_u(b[j] - bf2f(ub));
    }
}

// ============ prep: K -> bf16 hi/lo planes; V -> transposed bf16 plane ============
__global__ __launch_bounds__(256) void prep_kernel(
    const float* __restrict__ K, const float* __restrict__ V,
    unsigned short* __restrict__ Khi, unsigned short* __restrict__ Klo,
    unsigned short* __restrict__ Vt)
{
    __shared__ float vtile[64][65];
    const int t  = threadIdx.x;
    const int b  = blockIdx.x >> 5;
    const int s0 = (blockIdx.x & 31) << 6;
    const size_t base = ((size_t)b * SQ + s0) * DK + (size_t)t * 16;

    {
        short8 h0, l0, h1, l1;
        split8(K + base,     h0, l0);
        split8(K + base + 8, h1, l1);
        *(short8*)(Khi + base)     = h0;
        *(short8*)(Khi + base + 8) = h1;
        *(short8*)(Klo + base)     = l0;
        *(short8*)(Klo + base + 8) = l1;
    }
    {
        const int sr = t >> 2, dc = (t & 3) << 4;
        #pragma unroll
        for (int u = 0; u < 16; u += 4) {
            f32x4 v = *(const f32x4*)(V + base + u);
            vtile[sr][dc + u + 0] = v[0];
            vtile[sr][dc + u + 1] = v[1];
            vtile[sr][dc + u + 2] = v[2];
            vtile[sr][dc + u + 3] = v[3];
        }
    }
    __syncthreads();
    #pragma unroll
    for (int rep = 0; rep < 16; ++rep) {
        const int idx = rep * 256 + t;
        const int d = idx >> 6, s = idx & 63;
        Vt[((size_t)b * DK + d) * SQ + s0 + s] = (unsigned short)f2bf_u(vtile[s][d]);
    }
}

// ============ mkpack: int32 0/1 mask -> 1 bit per element ============
// word w covers mask elements [w*32, w*32+32); bit j <-> element w*32+j
__global__ __launch_bounds__(256) void mkpack_kernel(
    const unsigned* __restrict__ Mk, unsigned* __restrict__ Mkb)
{
    const size_t w = (size_t)blockIdx.x * 256 + threadIdx.x;
    const unsigned* p = Mk + w * 32;
    unsigned bits = 0;
    #pragma unroll
    for (int j = 0; j < 8; ++j) {
        const u32x4 v = *(const u32x4*)(p + j * 4);
        bits |= (v[0] ? 1u : 0u) << (j * 4 + 0);
        bits |= (v[1] ? 1u : 0u) << (j * 4 + 1);
        bits |= (v[2] ? 1u : 0u) << (j * 4 + 2);
        bits |= (v[3] ? 1u : 0u) << (j * 4 + 3);
    }
    Mkb[w] = bits;
}

// ============ main fused kernel: 32 q-rows, 1024 threads, 16 waves ============
__global__ __launch_bounds__(1024, 4) void sdpa_main(
    const float* __restrict__ Q, const unsigned short* __restrict__ Khi,
    const unsigned short* __restrict__ Klo, const unsigned short* __restrict__ Vt,
    const unsigned* __restrict__ Mkb, float* __restrict__ Yout, float* __restrict__ Aout)
{
    __shared__ __align__(16) unsigned short e_lds[TQ][EW];  // 132096 B, masked-e bf16
    __shared__ float yp[2][4][16][16];                      // 8 KB
    __shared__ float rsum[16][TQ];                          // 2 KB
    __shared__ float i2s[TQ];

    const int tid  = threadIdx.x;
    const int lane = tid & 63;
    const int wv   = tid >> 6;          // 0..15
    const int m16  = lane & 15;
    const int kq   = lane >> 4;
    const int koff = kq * 8;

    // XCD batch-affinity swizzle: XCD x owns batches 4x..4x+3
    const int bx  = blockIdx.x;
    const int xcd = bx & 7;
    const int j   = bx >> 3;            // 0..255
    const int b   = xcd * 4 + (j >> 6);
    const int q0  = (j & 63) * TQ;

    // Q fragments for BOTH q-halves (B-operand), split bf16
    short8 qh0[2], ql0[2], qh1[2], ql1[2];
    {
        const float* qr0 = Q + ((size_t)b * SQ + q0 + m16) * DK;
        split8(qr0 + koff,      qh0[0], ql0[0]);
        split8(qr0 + 32 + koff, qh0[1], ql0[1]);
        const float* qr1 = qr0 + 16 * DK;
        split8(qr1 + koff,      qh1[0], ql1[0]);
        split8(qr1 + 32 + koff, qh1[1], ql1[1]);
    }

    // bitmask for this wave's 128-k strip (L2-resident, tiny)
    const int ks = wv;                  // k-strip [ks*128, ks*128+128)
    const u32x4 mw0 = *(const u32x4*)(Mkb + ((size_t)b * SQ + q0 + m16) * (SQ / 32) + ks * 4);
    const u32x4 mw1 = *(const u32x4*)(Mkb + ((size_t)b * SQ + q0 + 16 + m16) * (SQ / 32) + ks * 4);

    // ---- Phase A: e = mask * exp(QK^T/8) for both q-halves -> bf16 LDS ----
    float rs0 = 0.f, rs1 = 0.f;
    {
        const size_t krow = ((size_t)b * SQ + ks * 128 + m16) * DK;
        const unsigned short* khp = Khi + krow;
        const unsigned short* klp = Klo + krow;
        const int xw = (m16 & 7) << 3;
        #pragma unroll
        for (int t = 0; t < 8; ++t) {
            const int off = t * 16 * DK;
            const short8 kh0 = *(const short8*)(khp + off + koff);
            const short8 kh1 = *(const short8*)(khp + off + 32 + koff);
            const short8 kl0 = *(const short8*)(klp + off + koff);
            const short8 kl1 = *(const short8*)(klp + off + 32 + koff);

            // q-half 0
            {
                f32x4 a0 = {0.f, 0.f, 0.f, 0.f};
                f32x4 a1 = {0.f, 0.f, 0.f, 0.f};
                a0 = __builtin_amdgcn_mfma_f32_16x16x32_bf16(kh0, qh0[0], a0, 0, 0, 0);
                a1 = __builtin_amdgcn_mfma_f32_16x16x32_bf16(kh1, qh0[1], a1, 0, 0, 0);
                a0 = __builtin_amdgcn_mfma_f32_16x16x32_bf16(kh0, ql0[0], a0, 0, 0, 0);
                a1 = __builtin_amdgcn_mfma_f32_16x16x32_bf16(kh1, ql0[1], a1, 0, 0, 0);
                a0 = __builtin_amdgcn_mfma_f32_16x16x32_bf16(kl0, qh0[0], a0, 0, 0, 0);
                a1 = __builtin_amdgcn_mfma_f32_16x16x32_bf16(kl1, qh0[1], a1, 0, 0, 0);
                const float e0 = __builtin_amdgcn_exp2f((a0[0] + a1[0]) * SCL);
                const float e1 = __builtin_amdgcn_exp2f((a0[1] + a1[1]) * SCL);
                const float e2 = __builtin_amdgcn_exp2f((a0[2] + a1[2]) * SCL);
                const float e3 = __builtin_amdgcn_exp2f((a0[3] + a1[3]) * SCL);
                rs0 += (e0 + e1) + (e2 + e3);
                const unsigned bits = (mw0[t >> 1] >> ((t & 1) * 16 + kq * 4)) & 0xfu;
                const float m0 = (bits & 1u) ? e0 : 0.f;
                const float m1 = (bits & 2u) ? e1 : 0.f;
                const float m2 = (bits & 4u) ? e2 : 0.f;
                const float m3 = (bits & 8u) ? e3 : 0.f;
                u32x2 pk;
                pk[0] = cvtpk_bf16(m0, m1);
                pk[1] = cvtpk_bf16(m2, m3);
                *(u32x2*)&e_lds[m16][(ks * 128 + t * 16 + kq * 4) ^ xw] = pk;
            }
            // q-half 1
            {
                f32x4 a0 = {0.f, 0.f, 0.f, 0.f};
                f32x4 a1 = {0.f, 0.f, 0.f, 0.f};
                a0 = __builtin_amdgcn_mfma_f32_16x16x32_bf16(kh0, qh1[0], a0, 0, 0, 0);
                a1 = __builtin_amdgcn_mfma_f32_16x16x32_bf16(kh1, qh1[1], a1, 0, 0, 0);
                a0 = __builtin_amdgcn_mfma_f32_16x16x32_bf16(kh0, ql1[0], a0, 0, 0, 0);
                a1 = __builtin_amdgcn_mfma_f32_16x16x32_bf16(kh1, ql1[1], a1, 0, 0, 0);
                a0 = __builtin_amdgcn_mfma_f32_16x16x32_bf16(kl0, qh1[0], a0, 0, 0, 0);
                a1 = __builtin_amdgcn_mfma_f32_16x16x32_bf16(kl1, qh1[1], a1, 0, 0, 0);
                const float e0 = __builtin_amdgcn_exp2f((a0[0] + a1[0]) * SCL);
                const float e1 = __builtin_amdgcn_exp2f((a0[1] + a1[1]) * SCL);
                const float e2 = __builtin_amdgcn_exp2f((a0[2] + a1[2]) * SCL);
                const float e3 = __builtin_amdgcn_exp2f((a0[3] + a1[3]) * SCL);
                rs1 += (e0 + e1) + (e2 + e3);
                const unsigned bits = (mw1[t >> 1] >> ((t & 1) * 16 + kq * 4)) & 0xfu;
                const float m0 = (bits & 1u) ? e0 : 0.f;
                const float m1 = (bits & 2u) ? e1 : 0.f;
                const float m2 = (bits & 4u) ? e2 : 0.f;
                const float m3 = (bits & 8u) ? e3 : 0.f;
                u32x2 pk;
                pk[0] = cvtpk_bf16(m0, m1);
                pk[1] = cvtpk_bf16(m2, m3);
                *(u32x2*)&e_lds[16 + m16][(ks * 128 + t * 16 + kq * 4) ^ xw] = pk;
            }
        }
    }
    rs0 += __shfl_xor(rs0, 16);
    rs0 += __shfl_xor(rs0, 32);
    rs1 += __shfl_xor(rs1, 16);
    rs1 += __shfl_xor(rs1, 32);
    if (lane < 16) {
        rsum[wv][lane]      = rs0;
        rsum[wv][16 + lane] = rs1;
    }
    __syncthreads();
    if (tid < TQ) {
        float s = 0.f;
        #pragma unroll
        for (int w = 0; w < 16; ++w) s += rsum[w][tid];
        i2s[tid] = 2.0f / s;       // includes dropout keep-scale
    }
    __syncthreads();

    // ---- CD phase (barrier-free): attn NT store + PV MFMA ----
    const int cr = tid >> 5;            // 0..31 (attn row)
    const int cc = (tid & 31) * 8;      // col base within 256-stripe
    const int xc = (cr & 7) << 3;
    const float i2 = i2s[cr];
    const size_t crow = ((size_t)b * SQ + q0 + cr) * SQ + cc;

    const int qg  = wv >> 3;            // q-half
    const int g   = (wv >> 1) & 3;      // d-group
    const int par = wv & 1;             // k-parity (1024 each)
    const int xm  = (m16 & 7) << 3;
    const int erow = qg * 16 + m16;
    const int xe  = (erow & 7) << 3;
    const unsigned short* vrow = Vt + ((size_t)b * DK + g * 16 + m16) * SQ + par * 1024;
    f32x4 acc = {0.f, 0.f, 0.f, 0.f};

    #define CSTRIPE(s)                                                            \
    {                                                                             \
        const u32x4 ev = *(const u32x4*)&e_lds[cr][((s) * 256 + cc) ^ xc];        \
        f32x4 o0, o1;                                                             \
        o0[0] = bf2f(ev[0] & 0xffffu) * i2;  o0[1] = bf2f_hi(ev[0]) * i2;         \
        o0[2] = bf2f(ev[1] & 0xffffu) * i2;  o0[3] = bf2f_hi(ev[1]) * i2;         \
        o1[0] = bf2f(ev[2] & 0xffffu) * i2;  o1[1] = bf2f_hi(ev[2]) * i2;         \
        o1[2] = bf2f(ev[3] & 0xffffu) * i2;  o1[3] = bf2f_hi(ev[3]) * i2;         \
        __builtin_nontemporal_store(o0, (f32x4*)(Aout + crow + (s) * 256));       \
        __builtin_nontemporal_store(o1, (f32x4*)(Aout + crow + (s) * 256 + 4));   \
    }
    #define PVCHUNK4(c0)                                                          \
    {                                                                             \
        _Pragma("unroll")                                                         \
        for (int c = (c0); c < (c0) + 4; ++c) {                                   \
            const int kl = par * 1024 + c * 32;                                   \
            const short8 af = *(const short8*)&e_lds[erow][(kl + koff) ^ xe];     \
            const short8 vf = *(const short8*)(vrow + c * 32 + koff);             \
            acc = __builtin_amdgcn_mfma_f32_16x16x32_bf16(af, vf, acc, 0, 0, 0);  \
        }                                                                         \
    }

    CSTRIPE(0) PVCHUNK4(0)
    CSTRIPE(1) PVCHUNK4(4)
    CSTRIPE(2) PVCHUNK4(8)
    CSTRIPE(3) PVCHUNK4(12)
    CSTRIPE(4) PVCHUNK4(16)
    CSTRIPE(5) PVCHUNK4(20)
    CSTRIPE(6) PVCHUNK4(24)
    CSTRIPE(7) PVCHUNK4(28)

    #undef PVCHUNK4
    #undef CSTRIPE

    // ---- combine k-parities, normalize, write y ----
    if (par == 1) {
        #pragma unroll
        for (int r = 0; r < 4; ++r) yp[qg][g][kq * 4 + r][m16] = acc[r];
    }
    __syncthreads();
    if (par == 0) {
        #pragma unroll
        for (int r = 0; r < 4; ++r) {
            const float yv = (acc[r] + yp[qg][g][kq * 4 + r][m16]) * i2s[qg * 16 + kq * 4 + r];
            Yout[((size_t)b * SQ + q0 + qg * 16 + kq * 4 + r) * DK + g * 16 + m16] = yv;
        }
    }
}

extern "C" void kernel_launch(void* const* d_in, const int* in_sizes, int n_in,
                              void* d_out, int out_size, void* d_ws, size_t ws_size,
                              hipStream_t stream) {
    const float*    Q  = (const float*)d_in[0];
    const float*    K  = (const float*)d_in[1];
    const float*    V  = (const float*)d_in[2];
    const unsigned* Mk = (const unsigned*)d_in[3];
    float* Yout = (float*)d_out;
    float* Aout = (float*)d_out + (size_t)NB * SQ * DK;

    const size_t NEL = (size_t)NB * SQ * DK;
    unsigned short* Khi = (unsigned short*)d_ws;
    unsigned short* Klo = Khi + NEL;
    unsigned short* Vt  = Klo + NEL;
    unsigned*       Mkb = (unsigned*)(Vt + NEL);   // 32*2048*64 words = 16.8 MB

    prep_kernel<<<dim3(NB * (SQ / 64)), dim3(256), 0, stream>>>(K, V, Khi, Klo, Vt);
    mkpack_kernel<<<dim3((NB * SQ * (SQ / 32)) / 256), dim3(256), 0, stream>>>(Mk, Mkb);
    sdpa_main<<<dim3(NB * (SQ / TQ)), dim3(1024), 0, stream>>>(
        Q, Khi, Klo, Vt, Mkb, Yout, Aout);
}